// Round 3
// baseline (62557.007 us; speedup 1.0000x reference)
//
#include <hip/hip_runtime.h>
#include <math.h>

#define SEQ 1024
#define BB  64
#define INF 512
#define HH  512
#define W0LD 1024          // W0 row stride (HH+INF)
#define TSLICE 32768       // 64*512 elements per t-slice
#define NWG 256

// ---------------------------------------------------------------------------
// Precompute kernel (unchanged from R2, passed): xw[t][j][b] = x[t,b,:]·W0[j,:512]
// stored transposed per t, aliased onto d_out's t-slice.
// ---------------------------------------------------------------------------
__global__ __launch_bounds__(256) void xw0_gemm(
    const float* __restrict__ x, const float* __restrict__ W0,
    float* __restrict__ xw)
{
    const int bid = blockIdx.x;
    const int t   = bid >> 3;
    const int jt  = bid & 7;
    const int tid = threadIdx.x;

    __shared__ float xs[64][68];
    __shared__ float ws[64][68];

    const int bq = tid & 15;
    const int jq = tid >> 4;
    float acc[4][4];
    #pragma unroll
    for (int i = 0; i < 4; ++i)
        #pragma unroll
        for (int k = 0; k < 4; ++k) acc[i][k] = 0.f;

    const int r = tid >> 2, q = tid & 3;
    const float* xrow = x  + (size_t)t * BB * INF + (size_t)r * INF;
    const float* wrow = W0 + (size_t)(jt * 64 + r) * W0LD;

    for (int kc = 0; kc < 512; kc += 64) {
        #pragma unroll
        for (int u = 0; u < 4; ++u) {
            const int k0 = 4 * q + 16 * u;
            float4 xv = *reinterpret_cast<const float4*>(xrow + kc + k0);
            xs[k0 + 0][r] = xv.x; xs[k0 + 1][r] = xv.y;
            xs[k0 + 2][r] = xv.z; xs[k0 + 3][r] = xv.w;
            float4 wv = *reinterpret_cast<const float4*>(wrow + kc + k0);
            ws[k0 + 0][r] = wv.x; ws[k0 + 1][r] = wv.y;
            ws[k0 + 2][r] = wv.z; ws[k0 + 3][r] = wv.w;
        }
        __syncthreads();
        #pragma unroll 16
        for (int k = 0; k < 64; ++k) {
            const float4 xv = *reinterpret_cast<const float4*>(&xs[k][bq * 4]);
            const float4 wv = *reinterpret_cast<const float4*>(&ws[k][jq * 4]);
            const float xa[4] = {xv.x, xv.y, xv.z, xv.w};
            const float wa[4] = {wv.x, wv.y, wv.z, wv.w};
            #pragma unroll
            for (int jj = 0; jj < 4; ++jj)
                #pragma unroll
                for (int bb = 0; bb < 4; ++bb)
                    acc[jj][bb] += wa[jj] * xa[bb];
        }
        __syncthreads();
    }

    float* dst = xw + (size_t)t * TSLICE;
    #pragma unroll
    for (int jj = 0; jj < 4; ++jj) {
        const int j = jt * 64 + jq * 4 + jj;
        float4 v = make_float4(acc[jj][0], acc[jj][1], acc[jj][2], acc[jj][3]);
        *reinterpret_cast<float4*>(dst + (size_t)j * 64 + bq * 4) = v;
    }
}

// ---------------------------------------------------------------------------
// Grid barrier: all waves drain stores to L2, leader does agent release
// (L2 writeback) -> atomic arrive -> spin -> agent acquire (L2 inv).
// ---------------------------------------------------------------------------
__device__ __forceinline__ void gbar(int* cnt, int* gen)
{
    asm volatile("s_waitcnt vmcnt(0)" ::: "memory");
    __syncthreads();
    if (threadIdx.x == 0) {
        __threadfence();   // release: wb L2 so other XCDs can see our stores
        int g = __hip_atomic_load(gen, __ATOMIC_RELAXED, __HIP_MEMORY_SCOPE_AGENT);
        int a = __hip_atomic_fetch_add(cnt, 1, __ATOMIC_RELAXED, __HIP_MEMORY_SCOPE_AGENT);
        if (a == NWG - 1) {
            __hip_atomic_store(cnt, 0, __ATOMIC_RELAXED, __HIP_MEMORY_SCOPE_AGENT);
            __hip_atomic_store(gen, g + 1, __ATOMIC_RELEASE, __HIP_MEMORY_SCOPE_AGENT);
        } else {
            while (__hip_atomic_load(gen, __ATOMIC_RELAXED, __HIP_MEMORY_SCOPE_AGENT) == g)
                __builtin_amdgcn_s_sleep(2);
        }
        __threadfence();   // acquire: inv L1/L2 so we see other XCDs' stores
    }
    __syncthreads();
}

// ---------------------------------------------------------------------------
// Persistent kernel: 256 WGs x 256 threads. WG w owns output columns
// j in {2w, 2w+1}. Weights for those columns live in LDS for all 1024 steps.
// Per step: phase A (layer1 c-half + hoisted xw + bias + relu -> hT),
// barrier, phase B (layer2 4 gates + epilogue -> cT, out[t]), barrier.
// Thread mapping both phases: b = tid&63, jl = bit6, kh/gh = bit7.
// ---------------------------------------------------------------------------
__global__ __launch_bounds__(256) void dlstm_persist(
    const float* __restrict__ W0, const float* __restrict__ b0,
    const float* __restrict__ W1, const float* __restrict__ b1,
    float* __restrict__ out, float* __restrict__ cT, float* __restrict__ hT,
    int* __restrict__ bcnt, int* __restrict__ bgen)
{
    const int wg  = blockIdx.x;
    const int tid = threadIdx.x;
    const int b   = tid & 63;
    const int jl  = (tid >> 6) & 1;
    const int kh  = tid >> 7;          // phase A: K-half ; phase B: gate-pair
    const int j   = wg * 2 + jl;

    __shared__ float wA[2][512];        // layer1 c-half rows   (4 KB)
    __shared__ float wB[2][2][512][2];  // layer2 [jl][gh][k][gate-in-pair] (16 KB)
    __shared__ float redA[2][64];
    __shared__ float redB[2][64][2];

    // ---- stage weights into LDS (once) ----
    for (int i = tid; i < 2 * 512; i += 256) {
        const int sjl = i >> 9, k = i & 511;
        wA[sjl][k] = W0[(size_t)(wg * 2 + sjl) * W0LD + INF + k];
    }
    for (int i = tid; i < 4096; i += 256) {
        const int p   = i & 1;
        const int k   = (i >> 1) & 511;
        const int sgh = (i >> 10) & 1;
        const int sjl = (i >> 11) & 1;
        wB[sjl][sgh][k][p] =
            W1[(size_t)((2 * sgh + p) * HH + wg * 2 + sjl) * HH + k];
    }
    const float b0j = b0[j];
    const float b1a = b1[(2 * kh + 0) * HH + j];
    const float b1b = b1[(2 * kh + 1) * HH + j];
    __syncthreads();

    const float* __restrict__ xwp = out + (size_t)j * 64 + b;  // xw[t][j][b]
    const int jj64b = j * 64 + b;

    for (int t = 0; t < SEQ; ++t) {
        // ---------------- phase A: h = relu(xw + c @ W0c^T + b0) ----------
        {
            const float* __restrict__ cp = cT + (kh << 8) * 64 + b;
            const float* __restrict__ wa = &wA[jl][kh << 8];
            float acc = 0.f;
            #pragma unroll 8
            for (int k = 0; k < 256; k += 4) {
                const float4 w = *reinterpret_cast<const float4*>(wa + k);
                acc += cp[(k + 0) * 64] * w.x + cp[(k + 1) * 64] * w.y +
                       cp[(k + 2) * 64] * w.z + cp[(k + 3) * 64] * w.w;
            }
            if (kh == 1) redA[jl][b] = acc;
            __syncthreads();
            if (kh == 0) {
                const float tot = acc + redA[jl][b] + b0j + xwp[(size_t)t * TSLICE];
                hT[jj64b] = fmaxf(tot, 0.f);
            }
        }
        gbar(bcnt, bgen);

        // ---------------- phase B: y = h @ W1^T + b1, epilogue ------------
        {
            const float* __restrict__ hp = hT + b;
            const float* __restrict__ wb = &wB[jl][kh][0][0];
            float a0 = 0.f, a1 = 0.f;
            #pragma unroll 8
            for (int k = 0; k < 512; k += 2) {
                const float4 w = *reinterpret_cast<const float4*>(wb + 2 * k);
                const float h0 = hp[(k + 0) * 64];
                const float h1 = hp[(k + 1) * 64];
                a0 += h0 * w.x + h1 * w.z;
                a1 += h0 * w.y + h1 * w.w;
            }
            a0 += b1a;
            a1 += b1b;
            if (kh == 1) { redB[jl][b][0] = a0; redB[jl][b][1] = a1; }
            __syncthreads();
            if (kh == 0) {
                const float yh  = redB[jl][b][0];                    // new_hx
                const float yf  = redB[jl][b][1];                    // forget
                const float ncx = fmaxf(a0, 0.f) - fmaxf(a1, 0.f);   // drelu
                const float f   = 1.f / (1.f + expf(-yf));
                const float cn  = f * ncx + (1.f - f) * cT[jj64b];
                cT[jj64b] = cn;
                out[(size_t)t * TSLICE + (size_t)b * HH + j] = fmaxf(yh, 0.f);
                if (t == SEQ - 1)
                    out[(size_t)SEQ * TSLICE + (size_t)b * HH + j] = cn;
            }
        }
        gbar(bcnt, bgen);
    }
}

// ---------------------------------------------------------------------------
extern "C" void kernel_launch(void* const* d_in, const int* in_sizes, int n_in,
                              void* d_out, int out_size, void* d_ws, size_t ws_size,
                              hipStream_t stream)
{
    const float* x  = (const float*)d_in[0];   // (SEQ, B, IN)
    const float* W0 = (const float*)d_in[1];   // (H, H+IN)
    const float* b0 = (const float*)d_in[2];   // (H)
    const float* W1 = (const float*)d_in[3];   // (4H, H)
    const float* b1 = (const float*)d_in[4];   // (4H)

    float* out = (float*)d_out;                        // (SEQ,B,H) + (1,B,H)

    int*   bcnt = (int*)d_ws;                          // barrier counter
    int*   bgen = bcnt + 1;                            // barrier generation
    float* cT   = (float*)((char*)d_ws + 1024);        // c [k][b], 128 KB
    float* hT   = cT + (size_t)HH * BB;                // h [k][b], 128 KB

    // zero barrier state + c0 (d_ws is re-poisoned before every run)
    hipMemsetAsync(d_ws, 0, 1024 + (size_t)HH * BB * sizeof(float), stream);

    // Hoisted x-part of layer 0, written transposed into d_out's t-slices.
    xw0_gemm<<<8192, 256, 0, stream>>>(x, W0, out);

    dlstm_persist<<<NWG, 256, 0, stream>>>(W0, b0, W1, b1, out, cT, hT,
                                           bcnt, bgen);
}

// Round 4
// 35641.000 us; speedup vs baseline: 1.7552x; 1.7552x over previous
//
#include <hip/hip_runtime.h>
#include <math.h>

#define SEQ 1024
#define BB  64
#define INF 512
#define HH  512
#define W0LD 1024          // W0 row stride (HH+INF)
#define TSLICE 32768       // 64*512 elements per t-slice
#define NGROUP 4           // independent batch groups
#define WGPG 64            // workgroups per group
#define GB 16              // batches per group

#define AGENT __HIP_MEMORY_SCOPE_AGENT

// ---------------------------------------------------------------------------
// Zero the barrier state at the coherent point (memset's cached zeros are not
// guaranteed visible to sc1 atomics — init from the device instead).
// ---------------------------------------------------------------------------
__global__ void init_barriers(int* bar)
{
    if (threadIdx.x < 2 * NGROUP)
        __hip_atomic_store(&bar[threadIdx.x], 0, __ATOMIC_RELAXED, AGENT);
}

// ---------------------------------------------------------------------------
// Precompute: xw[t][g][j][b4] = x[t, 16g+b4, :]·W0[j, :512]  (x-half of layer0)
// stored per-group-slab (8192 elems) inside d_out's t-slice, so group g's
// phase-A reads and phase-B out-writes touch only g's own slab.
// ---------------------------------------------------------------------------
__global__ __launch_bounds__(256) void xw0_gemm(
    const float* __restrict__ x, const float* __restrict__ W0,
    float* __restrict__ xw)
{
    const int bid = blockIdx.x;
    const int t   = bid >> 3;
    const int jt  = bid & 7;
    const int tid = threadIdx.x;

    __shared__ float xs[64][68];
    __shared__ float ws[64][68];

    const int bq = tid & 15;
    const int jq = tid >> 4;
    float acc[4][4];
    #pragma unroll
    for (int i = 0; i < 4; ++i)
        #pragma unroll
        for (int k = 0; k < 4; ++k) acc[i][k] = 0.f;

    const int r = tid >> 2, q = tid & 3;
    const float* xrow = x  + (size_t)t * BB * INF + (size_t)r * INF;
    const float* wrow = W0 + (size_t)(jt * 64 + r) * W0LD;

    for (int kc = 0; kc < 512; kc += 64) {
        #pragma unroll
        for (int u = 0; u < 4; ++u) {
            const int k0 = 4 * q + 16 * u;
            float4 xv = *reinterpret_cast<const float4*>(xrow + kc + k0);
            xs[k0 + 0][r] = xv.x; xs[k0 + 1][r] = xv.y;
            xs[k0 + 2][r] = xv.z; xs[k0 + 3][r] = xv.w;
            float4 wv = *reinterpret_cast<const float4*>(wrow + kc + k0);
            ws[k0 + 0][r] = wv.x; ws[k0 + 1][r] = wv.y;
            ws[k0 + 2][r] = wv.z; ws[k0 + 3][r] = wv.w;
        }
        __syncthreads();
        #pragma unroll 16
        for (int k = 0; k < 64; ++k) {
            const float4 xv = *reinterpret_cast<const float4*>(&xs[k][bq * 4]);
            const float4 wv = *reinterpret_cast<const float4*>(&ws[k][jq * 4]);
            const float xa[4] = {xv.x, xv.y, xv.z, xv.w};
            const float wa[4] = {wv.x, wv.y, wv.z, wv.w};
            #pragma unroll
            for (int jj = 0; jj < 4; ++jj)
                #pragma unroll
                for (int bb = 0; bb < 4; ++bb)
                    acc[jj][bb] += wa[jj] * xa[bb];
        }
        __syncthreads();
    }

    // slab layout: t*32768 + g*8192 + j*16 + b4 ;  b = bq*4+bb, g = bq>>2
    float* dst = xw + (size_t)t * TSLICE + (size_t)(bq >> 2) * 8192 + (bq & 3) * 4;
    #pragma unroll
    for (int jj = 0; jj < 4; ++jj) {
        const int j = jt * 64 + jq * 4 + jj;
        float4 v = make_float4(acc[jj][0], acc[jj][1], acc[jj][2], acc[jj][3]);
        *reinterpret_cast<float4*>(dst + (size_t)j * 16) = v;
    }
}

// ---------------------------------------------------------------------------
// Fence-free group barrier. Monotonic arrival counter; phase p's last arriver
// (arrival index p*WGPG+WGPG-1) publishes gen = p+1. Spin condition gen <= p
// is stale-read-safe (stale gen only delays release). Data visibility comes
// from sc1 (agent-scope atomic) state accesses + vmcnt(0) drain before arrive.
// ---------------------------------------------------------------------------
__device__ __forceinline__ void gbar(int* cnt, int* gen)
{
    asm volatile("s_waitcnt vmcnt(0)" ::: "memory");
    __syncthreads();
    if (threadIdx.x == 0) {
        int a = __hip_atomic_fetch_add(cnt, 1, __ATOMIC_RELAXED, AGENT);
        int p = a >> 6;                    // a / WGPG
        if ((a & (WGPG - 1)) == WGPG - 1) {
            __hip_atomic_store(gen, p + 1, __ATOMIC_RELAXED, AGENT);
        } else {
            while (__hip_atomic_load(gen, __ATOMIC_RELAXED, AGENT) <= p)
                __builtin_amdgcn_s_sleep(1);
        }
    }
    __syncthreads();
}

// ---------------------------------------------------------------------------
// Persistent kernel: 256 WGs x 1024 threads = 1 WG/CU, 16 waves/CU.
// WG (g = bid>>6, jt = bid&63) owns j in [8jt, 8jt+8), b in [16g, 16g+16).
// tid bits: b4 = tid&15, j8 = (tid>>4)&7, phase A ksA = tid>>7 (8-way K-split),
// phase B gh = (tid>>7)&1 (gate pair), ksB = tid>>8 (4-way K-split).
// Weights: wave-coalesced fp32 b128 loads from global (L2-resident, ~5MB).
// State hT/cT: relaxed agent atomics (coherent). c_prev: register-resident.
// ---------------------------------------------------------------------------
__global__ __launch_bounds__(1024) void dlstm_persist(
    const float* __restrict__ W0, const float* __restrict__ b0,
    const float* __restrict__ W1, const float* __restrict__ b1,
    float* __restrict__ out, float* __restrict__ cT, float* __restrict__ hT,
    int* __restrict__ bar)
{
    const int wg  = blockIdx.x;
    const int g   = wg >> 6;
    const int jt  = wg & 63;
    const int tid = threadIdx.x;
    const int b4  = tid & 15;
    const int j8  = (tid >> 4) & 7;
    const int ksA = tid >> 7;          // 0..7
    const int gh  = (tid >> 7) & 1;    // 0,1
    const int ksB = tid >> 8;          // 0..3
    const int j   = jt * 8 + j8;
    const int b   = g * 16 + b4;
    const bool fin = (tid < 128);      // finalizer threads: (j8,b4), ksA=0 / ksB=0,gh=0

    int* bcnt = bar + g;
    int* bgen = bar + NGROUP + g;

    __shared__ float redA[8][8][16];        // [ksA][j8][b4]
    __shared__ float redB[4][2][8][16][2];  // [ksB][gh][j8][b4][gate-in-pair]

    // thread-constant weight pointers / biases
    const float* __restrict__ waP  = W0 + (size_t)j * W0LD + INF + ksA * 64;
    const float* __restrict__ wb0P = W1 + ((size_t)(2 * gh) * HH + j) * HH + ksB * 128;
    const float* __restrict__ wb1P = wb0P + (size_t)HH * HH;
    const float b0j = b0[j];
    const float b1v0 = b1[j], b1v1 = b1[HH + j], b1v2 = b1[2 * HH + j], b1v3 = b1[3 * HH + j];

    float creg = 0.f;                  // c_prev for (j,b), owned by finalizer

    const float* __restrict__ cpB = cT + (size_t)(ksA * 64) * 64 + b;   // phase A
    const float* __restrict__ hpB = hT + (size_t)(ksB * 128) * 64 + b;  // phase B
    float* __restrict__ xws = out + (size_t)g * 8192 + (size_t)j * 16 + b4;

    for (int t = 0; t < SEQ; ++t) {
        // ---------------- phase A: h = relu(xw + c @ W0c^T + b0) ----------
        float xwv = 0.f;
        if (fin) xwv = xws[(size_t)t * TSLICE];     // normal load (own slab)
        float acc = 0.f;
        if (t > 0) {
            #pragma unroll 4
            for (int k = 0; k < 64; k += 4) {
                const float4 w = *reinterpret_cast<const float4*>(waP + k);
                const float c0 = __hip_atomic_load(const_cast<float*>(cpB + (k + 0) * 64), __ATOMIC_RELAXED, AGENT);
                const float c1 = __hip_atomic_load(const_cast<float*>(cpB + (k + 1) * 64), __ATOMIC_RELAXED, AGENT);
                const float c2 = __hip_atomic_load(const_cast<float*>(cpB + (k + 2) * 64), __ATOMIC_RELAXED, AGENT);
                const float c3 = __hip_atomic_load(const_cast<float*>(cpB + (k + 3) * 64), __ATOMIC_RELAXED, AGENT);
                acc = fmaf(c0, w.x, fmaf(c1, w.y, fmaf(c2, w.z, fmaf(c3, w.w, acc))));
            }
        }
        redA[ksA][j8][b4] = acc;
        __syncthreads();
        if (fin) {
            float s = b0j + xwv;
            #pragma unroll
            for (int r = 0; r < 8; ++r) s += redA[r][j8][b4];
            s = fmaxf(s, 0.f);
            __hip_atomic_store(&hT[(size_t)j * 64 + b], s, __ATOMIC_RELAXED, AGENT);
        }
        gbar(bcnt, bgen);

        // ---------------- phase B: y = h @ W1^T + b1, epilogue ------------
        float a0 = 0.f, a1 = 0.f;
        #pragma unroll 4
        for (int k = 0; k < 128; k += 4) {
            const float4 u = *reinterpret_cast<const float4*>(wb0P + k);
            const float4 v = *reinterpret_cast<const float4*>(wb1P + k);
            const float h0 = __hip_atomic_load(const_cast<float*>(hpB + (k + 0) * 64), __ATOMIC_RELAXED, AGENT);
            const float h1 = __hip_atomic_load(const_cast<float*>(hpB + (k + 1) * 64), __ATOMIC_RELAXED, AGENT);
            const float h2 = __hip_atomic_load(const_cast<float*>(hpB + (k + 2) * 64), __ATOMIC_RELAXED, AGENT);
            const float h3 = __hip_atomic_load(const_cast<float*>(hpB + (k + 3) * 64), __ATOMIC_RELAXED, AGENT);
            a0 = fmaf(h0, u.x, fmaf(h1, u.y, fmaf(h2, u.z, fmaf(h3, u.w, a0))));
            a1 = fmaf(h0, v.x, fmaf(h1, v.y, fmaf(h2, v.z, fmaf(h3, v.w, a1))));
        }
        redB[ksB][gh][j8][b4][0] = a0;
        redB[ksB][gh][j8][b4][1] = a1;
        __syncthreads();
        if (fin) {
            float y0 = b1v0, y1 = b1v1, y2 = b1v2, y3 = b1v3;
            #pragma unroll
            for (int r = 0; r < 4; ++r) {
                y0 += redB[r][0][j8][b4][0];
                y1 += redB[r][0][j8][b4][1];
                y2 += redB[r][1][j8][b4][0];
                y3 += redB[r][1][j8][b4][1];
            }
            const float ncx = fmaxf(y0, 0.f) - fmaxf(y1, 0.f);   // drelu
            const float f   = 1.f / (1.f + expf(-y3));           // sigmoid(forget)
            const float cn  = f * ncx + (1.f - f) * creg;
            creg = cn;
            __hip_atomic_store(&cT[(size_t)j * 64 + b], cn, __ATOMIC_RELAXED, AGENT);
            out[(size_t)t * TSLICE + (size_t)b * HH + j] = fmaxf(y2, 0.f);
            if (t == SEQ - 1)
                out[(size_t)SEQ * TSLICE + (size_t)b * HH + j] = cn;
        }
        gbar(bcnt, bgen);
    }
}

// ---------------------------------------------------------------------------
extern "C" void kernel_launch(void* const* d_in, const int* in_sizes, int n_in,
                              void* d_out, int out_size, void* d_ws, size_t ws_size,
                              hipStream_t stream)
{
    const float* x  = (const float*)d_in[0];   // (SEQ, B, IN)
    const float* W0 = (const float*)d_in[1];   // (H, H+IN)
    const float* b0 = (const float*)d_in[2];   // (H)
    const float* W1 = (const float*)d_in[3];   // (4H, H)
    const float* b1 = (const float*)d_in[4];   // (4H)

    float* out = (float*)d_out;                        // (SEQ,B,H) + (1,B,H)

    int*   bar = (int*)d_ws;                           // 8 ints barrier state
    float* cT  = (float*)((char*)d_ws + 256);          // c [j][b], 128 KB
    float* hT  = cT + (size_t)HH * BB;                 // h [j][b], 128 KB

    init_barriers<<<1, 64, 0, stream>>>(bar);

    // Hoisted x-part of layer 0 -> per-group slabs inside d_out's t-slices.
    xw0_gemm<<<8192, 256, 0, stream>>>(x, W0, out);

    dlstm_persist<<<NGROUP * WGPG, 1024, 0, stream>>>(W0, b0, W1, b1, out,
                                                      cT, hT, bar);
}